// Round 11
// baseline (341.095 us; speedup 1.0000x reference)
//
#include <hip/hip_runtime.h>

#define CIN_B 512
#define CIN_F0 40
#define CIN_D 32
#define CIN_S 200

typedef _Float16 f16x8 __attribute__((ext_vector_type(8)));
typedef float floatx16 __attribute__((ext_vector_type(16)));

__device__ __forceinline__ unsigned short f2h(float f) {
    _Float16 h = (_Float16)f;           // RNE
    return *(unsigned short*)&h;
}
__device__ __forceinline__ float h2f(unsigned short u) {
    return (float)(*(_Float16*)&u);
}

// Wtk[kc][nn 0..255][kw 0..15] = f16(W[(i*FI + kk*16+kw)*200 + nn]); kc=i*KCPI+kk.
template <int FI, int KCPI>
__global__ __launch_bounds__(256) void prep_w(const float* __restrict__ W,
                                              unsigned short* __restrict__ Wtk) {
    const int kc = blockIdx.x;
    const int nn = threadIdx.x;
    const int i = kc / KCPI;
    const int kk = kc - i * KCPI;
    unsigned short v[16];
#pragma unroll
    for (int kw = 0; kw < 16; ++kw) {
        int j = kk * 16 + kw;
        float f = 0.f;
        if (j < FI && nn < CIN_S) f = W[(size_t)(i * FI + j) * CIN_S + nn];
        v[kw] = f2h(f);
    }
    uint4* dst = (uint4*)(Wtk + ((size_t)kc * 256 + nn) * 16);
    dst[0] = ((const uint4*)v)[0];
    dst[1] = ((const uint4*)v)[1];
}

// fused for the two big weight matrices; kc = i*13+kk, kk==6 stored 0.5x (read
// by BOTH j-halves: 0.5x + 0.5x == x; 0.5 scaling exact in fp16).
__global__ __launch_bounds__(256) void prep_w2(const float* __restrict__ Wa,
                                               unsigned short* __restrict__ Wta,
                                               const float* __restrict__ Wb,
                                               unsigned short* __restrict__ Wtb) {
    const int half = blockIdx.x >= 520;
    const int kc = half ? blockIdx.x - 520 : blockIdx.x;
    const float* W = half ? Wb : Wa;
    unsigned short* Wtk = half ? Wtb : Wta;
    const int nn = threadIdx.x;
    const int i = kc / 13;
    const int kk = kc - i * 13;
    const float sc = (kk == 6) ? 0.5f : 1.0f;
    unsigned short v[16];
#pragma unroll
    for (int kw = 0; kw < 16; ++kw) {
        int j = kk * 16 + kw;
        float f = 0.f;
        if (j < CIN_S && nn < CIN_S) f = sc * W[(size_t)(i * CIN_S + j) * CIN_S + nn];
        v[kw] = f2h(f);
    }
    uint4* dst = (uint4*)(Wtk + ((size_t)kc * 256 + nn) * 16);
    dst[0] = ((const uint4*)v)[0];
    dst[1] = ((const uint4*)v)[1];
}

// X0hd[b][d][i(pad 48)] = f16(x0[b][i][d])  (layer1 B-source, d-major)
// Xh[b][i][d] = f16(x0[b][i][d])            (scale source, all layers)
__global__ __launch_bounds__(256) void prep_x(const float* __restrict__ X,
                                              unsigned short* __restrict__ X0hd,
                                              unsigned short* __restrict__ Xh) {
    int e = blockIdx.x * 256 + threadIdx.x;   // 512*40*32
    int d = e & 31;
    int rest = e >> 5;
    int i = rest % CIN_F0;
    int b = rest / CIN_F0;
    unsigned short v = f2h(X[e]);
    Xh[e] = v;
    X0hd[((size_t)b * CIN_D + d) * 48 + i] = v;
    if (e < CIN_B * CIN_D * 8) {     // zero pads i=40..47
        int q = e & 7, dd = (e >> 3) & 31, bb = e >> 8;
        X0hd[((size_t)bb * CIN_D + dd) * 48 + 40 + q] = 0;
    }
}

// One layer (j-half per blockIdx.y for MODE 2/3). Block = 2 b x 7 waves (448).
// LOOP NEST: kk OUTER, i INNER. Per kk the 2 B-fragments are loaded from LDS
// ONCE (8 VGPRs) and reused for all 40 i -> 14 ds_read_b128 per wave total
// (was 560; LDS pipe was the 39us/CU bottleneck). x0 folded into B via
// v_pk_mul_f16; acc is the MFMA C operand (no P accumulator, 32 AGPRs).
// Small live set -> compiler can pipeline the unrolled independent A-loads.
// MODE 1: Hsrc=X0hd, unsplit, writes H1 + out direct.
// MODE 2: writes Hacc[jh][b][n][d] f16 partials + outp.
// MODE 3: combines the two jh partials of H2 during staging, writes outp only.
// mfma_f32_32x32x16_f16: A[m=lane&31][k=(lane>>5)*8+e]; B[k][col=lane&31];
// C/D col=lane&31, row=(reg&3)+8*(reg>>2)+4*(lane>>5).
template <int NKC, int KCPI_TOT, int MODE>
__global__ __launch_bounds__(448, 4)
void cin_layer(const unsigned short* __restrict__ Hsrc,
               const unsigned short* __restrict__ Xh,
               const unsigned short* __restrict__ Wtk,
               unsigned short* __restrict__ Hout,
               float* __restrict__ outp) {
    constexpr int JROW = (MODE == 1) ? 48 : 224;
    __shared__ __align__(16) unsigned short Bp[2 * NKC * 512];
    const int tid = threadIdx.x;
    const int b0 = blockIdx.x * 2;
    const int jh = (MODE == 1) ? 0 : blockIdx.y;
    const int kks = jh * 6;

    // ---- stage B-frags into LDS (fragment order, i-invariant) ----
    if constexpr (MODE != 3) {
        const int j0 = (MODE == 1) ? 0 : jh * 96;
        uint4* Bpu = (uint4*)Bp;
        for (int g = tid; g < 2 * 64 * NKC; g += 448) {
            int bb = g / (64 * NKC), r = g - bb * (64 * NKC);
            int d = r / (2 * NKC), c = r - d * (2 * NKC);
            uint4 v = ((const uint4*)Hsrc)[(((size_t)(b0 + bb) * CIN_D + d) * JROW + j0) / 8 + c];
            Bpu[(bb * NKC + (c >> 1)) * 64 + (c & 1) * 32 + d] = v;
        }
    } else {
        uint4* Bpu = (uint4*)Bp;
        for (int g = tid; g < 2 * NKC * 64; g += 448) {
            int bb = g / (NKC * 64), r = g - bb * (NKC * 64);
            int kk = r >> 6, r2 = r & 63, hl = r2 >> 5, d = r2 & 31;
            const unsigned short* p0 = Hsrc + ((size_t)(b0 + bb) * 208) * CIN_D + d;
            const unsigned short* p1 = p0 + (size_t)CIN_B * 208 * CIN_D;
            unsigned short v[8];
#pragma unroll
            for (int q = 0; q < 8; ++q) {
                int n = (kks + kk) * 16 + hl * 8 + q;
                v[q] = f2h(h2f(p0[(size_t)n * CIN_D]) + h2f(p1[(size_t)n * CIN_D]));
            }
            Bpu[(bb * NKC + kk) * 64 + hl * 32 + d] = *(const uint4*)v;
        }
    }
    __syncthreads();

    const int tile = tid >> 6;              // 0..6
    const int lane = tid & 63;
    const int l32 = lane & 31, hl = lane >> 5;

    const unsigned short* Abase =
        Wtk + ((size_t)(tile * 32 + l32) * 16 + hl * 8) + (size_t)kks * 4096;
    const _Float16* xp = (const _Float16*)Xh + (size_t)b0 * (CIN_F0 * CIN_D) + l32;

    floatx16 acc0, acc1;
#pragma unroll
    for (int r = 0; r < 16; ++r) { acc0[r] = 0.f; acc1[r] = 0.f; }

#pragma unroll 1
    for (int kk = 0; kk < NKC; ++kk) {
        const f16x8 Braw0 = *(const f16x8*)&Bp[(0 * NKC + kk) * 512 + lane * 8];
        const f16x8 Braw1 = *(const f16x8*)&Bp[(1 * NKC + kk) * 512 + lane * 8];
        const unsigned short* Ak = Abase + (size_t)kk * 4096;
#pragma unroll 4
        for (int i = 0; i < CIN_F0; ++i) {
            const f16x8 Af = *(const f16x8*)(Ak + (size_t)i * (KCPI_TOT * 4096));
            const _Float16 x0 = xp[i * CIN_D];
            const _Float16 x1 = xp[i * CIN_D + CIN_F0 * CIN_D];
            f16x8 xs0, xs1;
#pragma unroll
            for (int r = 0; r < 8; ++r) { xs0[r] = x0; xs1[r] = x1; }
            acc0 = __builtin_amdgcn_mfma_f32_32x32x16_f16(Af, Braw0 * xs0, acc0, 0, 0, 0);
            acc1 = __builtin_amdgcn_mfma_f32_32x32x16_f16(Af, Braw1 * xs1, acc1, 0, 0, 0);
        }
    }

    // ---- epilogue ----
#pragma unroll
    for (int bb = 0; bb < 2; ++bb) {
        const floatx16& a = bb ? acc1 : acc0;

        if constexpr (MODE == 1) {   // H1[b][d][n] f16, n-tile of 32
            unsigned short* dst =
                Hout + ((size_t)(b0 + bb) * CIN_D + l32) * 224 + tile * 32;
#pragma unroll
            for (int qd = 0; qd < 4; ++qd) {
                ushort4 pk;
                pk.x = f2h(a[4 * qd + 0]);
                pk.y = f2h(a[4 * qd + 1]);
                pk.z = f2h(a[4 * qd + 2]);
                pk.w = f2h(a[4 * qd + 3]);
                *(ushort4*)&dst[8 * qd + 4 * hl] = pk;
            }
        }
        if constexpr (MODE == 2) {   // Hacc[jh][b][n][d] f16, coalesced d
            unsigned short* hb =
                Hout + (((size_t)jh * CIN_B + b0 + bb) * 208) * CIN_D + l32;
#pragma unroll
            for (int r = 0; r < 16; ++r) {
                int n = tile * 32 + (r & 3) + 8 * (r >> 2) + 4 * hl;
                if (n < 208) hb[(size_t)n * CIN_D] = f2h(a[r]);
            }
        }

        // d-sum over col = l32 (fp32)
#pragma unroll
        for (int r = 0; r < 16; ++r) {
            float v = a[r];
            v += __shfl_xor(v, 1);
            v += __shfl_xor(v, 2);
            v += __shfl_xor(v, 4);
            v += __shfl_xor(v, 8);
            v += __shfl_xor(v, 16);
            if (l32 == 0) {
                int n = tile * 32 + (r & 3) + 8 * (r >> 2) + 4 * hl;
                if (n < CIN_S) {
                    if constexpr (MODE == 1)
                        outp[(size_t)(b0 + bb) * (3 * CIN_S) + n] = v;   // direct out
                    else
                        outp[((size_t)jh * CIN_B + b0 + bb) * CIN_S + n] = v;
                }
            }
        }
    }
}

// out[b, 200+t] from jh-partial sums (t in [0,400))
__global__ __launch_bounds__(256) void cin_outc(const float* __restrict__ p2,
                                                const float* __restrict__ p3,
                                                float* __restrict__ out) {
    int e = blockIdx.x * 256 + threadIdx.x;   // 512*400 exact
    int b = e / 400, t = e - b * 400;
    int half = t / 200, n = t - half * 200;
    const float* p = half ? p3 : p2;
    out[(size_t)b * 600 + 200 + half * 200 + n] =
        p[(size_t)b * CIN_S + n] + p[(size_t)(CIN_B + b) * CIN_S + n];
}

extern "C" void kernel_launch(void* const* d_in, const int* in_sizes, int n_in,
                              void* d_out, int out_size, void* d_ws, size_t ws_size,
                              hipStream_t stream) {
    const float* X  = (const float*)d_in[0];
    const float* W0 = (const float*)d_in[1];
    const float* W1 = (const float*)d_in[2];
    const float* W2 = (const float*)d_in[3];
    float* out = (float*)d_out;

    unsigned short* Wtk1 = (unsigned short*)d_ws;             // 120*4096
    unsigned short* Wtk2 = Wtk1 + (size_t)120 * 4096;         // 520*4096 each
    unsigned short* Wtk3 = Wtk2 + (size_t)520 * 4096;
    unsigned short* X0hd = Wtk3 + (size_t)520 * 4096;         // 512*32*48
    unsigned short* Xh   = X0hd + (size_t)CIN_B * CIN_D * 48; // 512*40*32
    unsigned short* H1   = Xh + (size_t)CIN_B * CIN_F0 * CIN_D; // 512*32*224
    unsigned short* Hacc = H1 + (size_t)CIN_B * CIN_D * 224;  // 2*512*208*32 f16
    float* outp2 = (float*)(Hacc + (size_t)2 * CIN_B * 208 * CIN_D);  // 2*512*200
    float* outp3 = outp2 + (size_t)2 * CIN_B * CIN_S;
    // total ws ~49 MB

    prep_w<CIN_F0, 3><<<120, 256, 0, stream>>>(W0, Wtk1);
    prep_w2<<<1040, 256, 0, stream>>>(W1, Wtk2, W2, Wtk3);
    prep_x<<<(CIN_B * CIN_F0 * CIN_D) / 256, 256, 0, stream>>>(X, X0hd, Xh);

    cin_layer<3, 3, 1><<<dim3(CIN_B / 2, 1), 448, 0, stream>>>(X0hd, Xh, Wtk1, H1, out);
    cin_layer<7, 13, 2><<<dim3(CIN_B / 2, 2), 448, 0, stream>>>(H1, Xh, Wtk2, Hacc, outp2);
    cin_layer<7, 13, 3><<<dim3(CIN_B / 2, 2), 448, 0, stream>>>(Hacc, Xh, Wtk3, nullptr, outp3);

    cin_outc<<<(CIN_B * 400) / 256, 256, 0, stream>>>(outp2, outp3, out);
}

// Round 13
// 311.384 us; speedup vs baseline: 1.0954x; 1.0954x over previous
//
#include <hip/hip_runtime.h>

#define CIN_B 512
#define CIN_F0 40
#define CIN_D 32
#define CIN_S 200

typedef _Float16 f16x8 __attribute__((ext_vector_type(8)));
typedef float floatx16 __attribute__((ext_vector_type(16)));

__device__ __forceinline__ unsigned short f2h(float f) {
    _Float16 h = (_Float16)f;           // RNE
    return *(unsigned short*)&h;
}
__device__ __forceinline__ float h2f(unsigned short u) {
    return (float)(*(_Float16*)&u);
}

// Wtk[kc][nn 0..255][kw 0..15] = f16(W[(i*FI + kk*16+kw)*200 + nn]); kc=i*KCPI+kk.
template <int FI, int KCPI>
__global__ __launch_bounds__(256) void prep_w(const float* __restrict__ W,
                                              unsigned short* __restrict__ Wtk) {
    const int kc = blockIdx.x;
    const int nn = threadIdx.x;
    const int i = kc / KCPI;
    const int kk = kc - i * KCPI;
    unsigned short v[16];
#pragma unroll
    for (int kw = 0; kw < 16; ++kw) {
        int j = kk * 16 + kw;
        float f = 0.f;
        if (j < FI && nn < CIN_S) f = W[(size_t)(i * FI + j) * CIN_S + nn];
        v[kw] = f2h(f);
    }
    uint4* dst = (uint4*)(Wtk + ((size_t)kc * 256 + nn) * 16);
    dst[0] = ((const uint4*)v)[0];
    dst[1] = ((const uint4*)v)[1];
}

// fused for the two big weight matrices; kc = i*13+kk, kk==6 stored 0.5x (read
// by BOTH j-halves: 0.5x + 0.5x == x; 0.5 scaling exact in fp16).
__global__ __launch_bounds__(256) void prep_w2(const float* __restrict__ Wa,
                                               unsigned short* __restrict__ Wta,
                                               const float* __restrict__ Wb,
                                               unsigned short* __restrict__ Wtb) {
    const int half = blockIdx.x >= 520;
    const int kc = half ? blockIdx.x - 520 : blockIdx.x;
    const float* W = half ? Wb : Wa;
    unsigned short* Wtk = half ? Wtb : Wta;
    const int nn = threadIdx.x;
    const int i = kc / 13;
    const int kk = kc - i * 13;
    const float sc = (kk == 6) ? 0.5f : 1.0f;
    unsigned short v[16];
#pragma unroll
    for (int kw = 0; kw < 16; ++kw) {
        int j = kk * 16 + kw;
        float f = 0.f;
        if (j < CIN_S && nn < CIN_S) f = sc * W[(size_t)(i * CIN_S + j) * CIN_S + nn];
        v[kw] = f2h(f);
    }
    uint4* dst = (uint4*)(Wtk + ((size_t)kc * 256 + nn) * 16);
    dst[0] = ((const uint4*)v)[0];
    dst[1] = ((const uint4*)v)[1];
}

// X0hd[b][d][i(pad 48)] = f16(x0[b][i][d]);  Xh[b][i][d] = f16(x0[b][i][d])
__global__ __launch_bounds__(256) void prep_x(const float* __restrict__ X,
                                              unsigned short* __restrict__ X0hd,
                                              unsigned short* __restrict__ Xh) {
    int e = blockIdx.x * 256 + threadIdx.x;   // 512*40*32
    int d = e & 31;
    int rest = e >> 5;
    int i = rest % CIN_F0;
    int b = rest / CIN_F0;
    unsigned short v = f2h(X[e]);
    Xh[e] = v;
    X0hd[((size_t)b * CIN_D + d) * 48 + i] = v;
    if (e < CIN_B * CIN_D * 8) {     // zero pads i=40..47
        int q = e & 7, dd = (e >> 3) & 31, bb = e >> 8;
        X0hd[((size_t)bb * CIN_D + dd) * 48 + 40 + q] = 0;
    }
}

// One layer (j-half per blockIdx.y for MODE 2/3). Block = 2 b x 7 waves (448).
// A-stream: async global_load_lds into TRIPLE-buffered wave-private LDS slots
// (G=2 steps/group): group g+2 writes buffer (g+2)%3, never the buffer being
// read this iteration (R12's 2-buffer overwrite race fixed). The main loop has
// ZERO vmem-to-VGPR loads: B-frags come from LDS (Bp, fragment order, lgkm),
// x from LDS (Xl) -> the vmcnt FIFO holds ONLY prefetch DMAs, so
// s_waitcnt vmcnt(2) exactly guards group g while group g+1 stays in flight.
// mfma_f32_32x32x16_f16: A[m=lane&31][k=(lane>>5)*8+e]; B[k][col=lane&31];
// C/D col=lane&31, row=(reg&3)+8*(reg>>2)+4*(lane>>5).
template <int NKC, int KCPI_TOT, int JROW, int MODE>
__global__ __launch_bounds__(448, 4)
void cin_layer(const unsigned short* __restrict__ Hsrc,
               const unsigned short* __restrict__ Xh,
               const unsigned short* __restrict__ Wtk,
               unsigned short* __restrict__ Hout,
               float* __restrict__ outp) {
    constexpr int NSTEP = NKC * 40;
    constexpr int G = 2;
    constexpr int NGRP = NSTEP / G;
    __shared__ __align__(16) unsigned short Abuf[3][7][G][512];  // 42 KB
    __shared__ __align__(16) unsigned short Bp[2 * NKC * 512];   // 6 / 14 KB
    __shared__ unsigned int Xl[CIN_F0 * CIN_D];                  // 5 KB

    const int tid = threadIdx.x;
    const int b0 = blockIdx.x * 2;
    const int jh = (MODE == 1) ? 0 : blockIdx.y;
    const int kks = jh * 6;

    // stage packed x-pairs: Xl[i*32+d] = x[b0][i][d] | x[b0+1][i][d]<<16
    for (int e = tid; e < CIN_F0 * CIN_D; e += 448) {
        unsigned int lo = Xh[(size_t)b0 * (CIN_F0 * CIN_D) + e];
        unsigned int hi = Xh[(size_t)(b0 + 1) * (CIN_F0 * CIN_D) + e];
        Xl[e] = lo | (hi << 16);
    }
    // stage B-frags into LDS (fragment order, i-invariant) — R10-proven layout
    {
        const int j0 = (MODE == 1) ? 0 : jh * 96;
        uint4* Bpu = (uint4*)Bp;
        for (int g = tid; g < 2 * 64 * NKC; g += 448) {
            int bb = g / (64 * NKC), r = g - bb * (64 * NKC);
            int d = r / (2 * NKC), c = r - d * (2 * NKC);
            uint4 v = ((const uint4*)Hsrc)[(((size_t)(b0 + bb) * CIN_D + d) * JROW + j0) / 8 + c];
            Bpu[(bb * NKC + (c >> 1)) * 64 + (c & 1) * 32 + d] = v;
        }
    }
    __syncthreads();

    const int wave = tid >> 6, lane = tid & 63;
    const int l32 = lane & 31, hl = lane >> 5;
    const int tile = wave;

    // per-lane global A fragment base (bytes): row tile*32+l32, col-half hl
    const char* Awb = (const char*)Wtk + (size_t)tile * 1024 + l32 * 32 + hl * 16;

    auto pfetch = [&](int s, int buf, int slot) {
        int ss = (s < NSTEP) ? s : (NSTEP - 1);
        int kk = ss / 40, ii = ss - kk * 40;
        const char* gp = Awb + (size_t)(ii * KCPI_TOT + kks + kk) * 8192;
        __builtin_amdgcn_global_load_lds(
            (const __attribute__((address_space(1))) void*)gp,
            (__attribute__((address_space(3))) void*)&Abuf[buf][wave][slot][0],
            16, 0, 0);
    };

#pragma unroll
    for (int q = 0; q < G; ++q) pfetch(q, 0, q);
#pragma unroll
    for (int q = 0; q < G; ++q) pfetch(G + q, 1, q);

    floatx16 acc0, acc1;
#pragma unroll
    for (int r = 0; r < 16; ++r) { acc0[r] = 0.f; acc1[r] = 0.f; }
    f16x8 Braw0{}, Braw1{};
    int curkk = -1;

#pragma unroll 1
    for (int g = 0; g < NGRP; ++g) {
        const int s0 = g * G;
        const int kk = s0 / 40;          // G divides 40: uniform within group
        const int i0 = s0 - kk * 40;
        if (kk != curkk) {               // 2 ds_read_b128 per kk (lgkm, not vm)
            curkk = kk;
            Braw0 = *(const f16x8*)&Bp[(0 * NKC + kk) * 512 + lane * 8];
            Braw1 = *(const f16x8*)&Bp[(1 * NKC + kk) * 512 + lane * 8];
        }
        // group g's DMA done; group g+1 (newest G) stays in flight
        asm volatile("s_waitcnt vmcnt(2)" ::: "memory");
        const unsigned short* Ab = &Abuf[g % 3][wave][0][0];
#pragma unroll
        for (int q = 0; q < G; ++q) {
            const f16x8 Af = *(const f16x8*)(Ab + q * 512 + lane * 8);
            const unsigned int xp = Xl[(i0 + q) * CIN_D + l32];
            union { f16x8 v; unsigned int w[4]; } xs0, xs1;
            const unsigned int lo2 = (xp & 0xffffu) | (xp << 16);
            const unsigned int hi2 = (xp >> 16) | (xp & 0xffff0000u);
            xs0.w[0] = xs0.w[1] = xs0.w[2] = xs0.w[3] = lo2;
            xs1.w[0] = xs1.w[1] = xs1.w[2] = xs1.w[3] = hi2;
            acc0 = __builtin_amdgcn_mfma_f32_32x32x16_f16(Af, Braw0 * xs0.v, acc0, 0, 0, 0);
            acc1 = __builtin_amdgcn_mfma_f32_32x32x16_f16(Af, Braw1 * xs1.v, acc1, 0, 0, 0);
        }
        asm volatile("" ::: "memory");   // pin: ds_reads above, DMA below
        const int gn = g + 2;            // target buffer gn%3 != g%3 (being read)
#pragma unroll
        for (int q = 0; q < G; ++q) pfetch(gn * G + q, gn % 3, q);
    }

    // ---- epilogue ----
#pragma unroll
    for (int bb = 0; bb < 2; ++bb) {
        const floatx16& a = bb ? acc1 : acc0;

        if constexpr (MODE == 1) {   // H1[b][d][n] f16, n-tile of 32
            unsigned short* dst =
                Hout + ((size_t)(b0 + bb) * CIN_D + l32) * 224 + tile * 32;
#pragma unroll
            for (int qd = 0; qd < 4; ++qd) {
                ushort4 pk;
                pk.x = f2h(a[4 * qd + 0]);
                pk.y = f2h(a[4 * qd + 1]);
                pk.z = f2h(a[4 * qd + 2]);
                pk.w = f2h(a[4 * qd + 3]);
                *(ushort4*)&dst[8 * qd + 4 * hl] = pk;
            }
        }
        if constexpr (MODE == 2) {   // Hacc[jh][b][n][d] f16 partials
            unsigned short* hb2 =
                Hout + (((size_t)jh * CIN_B + b0 + bb) * 208) * CIN_D + l32;
#pragma unroll
            for (int r = 0; r < 16; ++r) {
                int n = tile * 32 + (r & 3) + 8 * (r >> 2) + 4 * hl;
                if (n < 208) hb2[(size_t)n * CIN_D] = f2h(a[r]);
            }
        }

        // d-sum over col = l32 (fp32)
#pragma unroll
        for (int r = 0; r < 16; ++r) {
            float v = a[r];
            v += __shfl_xor(v, 1);
            v += __shfl_xor(v, 2);
            v += __shfl_xor(v, 4);
            v += __shfl_xor(v, 8);
            v += __shfl_xor(v, 16);
            if (l32 == 0) {
                int n = tile * 32 + (r & 3) + 8 * (r >> 2) + 4 * hl;
                if (n < CIN_S) {
                    if constexpr (MODE == 1)
                        outp[(size_t)(b0 + bb) * (3 * CIN_S) + n] = v;   // direct
                    else
                        outp[((size_t)jh * CIN_B + b0 + bb) * CIN_S + n] = v;
                }
            }
        }
    }
}

// combine jh-partials of layer2's H: H2c[b][d][n<208] = p0[b][n][d]+p1[b][n][d]
__global__ __launch_bounds__(256) void cin_comb(const unsigned short* __restrict__ Hacc,
                                                unsigned short* __restrict__ H2c) {
    __shared__ unsigned short T[208][33];
    const int b = blockIdx.x;
    const unsigned short* p0 = Hacc + (size_t)b * 208 * CIN_D;
    const unsigned short* p1 = p0 + (size_t)CIN_B * 208 * CIN_D;
    for (int e = threadIdx.x; e < 208 * CIN_D; e += 256) {
        T[e >> 5][e & 31] = f2h(h2f(p0[e]) + h2f(p1[e]));
    }
    __syncthreads();
    const int d = threadIdx.x >> 3, c = threadIdx.x & 7;   // 32 d x 8 chunks of 26
    unsigned short* dst = H2c + ((size_t)b * CIN_D + d) * 208 + c * 26;
#pragma unroll
    for (int q = 0; q < 26; ++q) dst[q] = T[c * 26 + q][d];
}

// out[b, 200+t] from jh-partial sums (t in [0,400))
__global__ __launch_bounds__(256) void cin_outc(const float* __restrict__ p2,
                                                const float* __restrict__ p3,
                                                float* __restrict__ out) {
    int e = blockIdx.x * 256 + threadIdx.x;   // 512*400 exact
    int b = e / 400, t = e - b * 400;
    int half = t / 200, n = t - half * 200;
    const float* p = half ? p3 : p2;
    out[(size_t)b * 600 + 200 + half * 200 + n] =
        p[(size_t)b * CIN_S + n] + p[(size_t)(CIN_B + b) * CIN_S + n];
}

extern "C" void kernel_launch(void* const* d_in, const int* in_sizes, int n_in,
                              void* d_out, int out_size, void* d_ws, size_t ws_size,
                              hipStream_t stream) {
    const float* X  = (const float*)d_in[0];
    const float* W0 = (const float*)d_in[1];
    const float* W1 = (const float*)d_in[2];
    const float* W2 = (const float*)d_in[3];
    float* out = (float*)d_out;

    unsigned short* Wtk1 = (unsigned short*)d_ws;             // 120*4096
    unsigned short* Wtk2 = Wtk1 + (size_t)120 * 4096;         // 520*4096 each
    unsigned short* Wtk3 = Wtk2 + (size_t)520 * 4096;
    unsigned short* X0hd = Wtk3 + (size_t)520 * 4096;         // 512*32*48
    unsigned short* Xh   = X0hd + (size_t)CIN_B * CIN_D * 48; // 512*40*32
    unsigned short* H1   = Xh + (size_t)CIN_B * CIN_F0 * CIN_D; // 512*32*224
    unsigned short* Hacc = H1 + (size_t)CIN_B * CIN_D * 224;  // 2*512*208*32 f16
    unsigned short* H2c  = Hacc + (size_t)2 * CIN_B * 208 * CIN_D; // 512*32*208
    float* outp2 = (float*)(H2c + (size_t)CIN_B * CIN_D * 208);    // 2*512*200
    float* outp3 = outp2 + (size_t)2 * CIN_B * CIN_S;
    // total ws ~47 MB

    prep_w<CIN_F0, 3><<<120, 256, 0, stream>>>(W0, Wtk1);
    prep_w2<<<1040, 256, 0, stream>>>(W1, Wtk2, W2, Wtk3);
    prep_x<<<(CIN_B * CIN_F0 * CIN_D) / 256, 256, 0, stream>>>(X, X0hd, Xh);

    cin_layer<3, 3, 48, 1><<<dim3(CIN_B / 2, 1), 448, 0, stream>>>(X0hd, Xh, Wtk1, H1, out);
    cin_layer<7, 13, 224, 2><<<dim3(CIN_B / 2, 2), 448, 0, stream>>>(H1, Xh, Wtk2, Hacc, outp2);
    cin_comb<<<CIN_B, 256, 0, stream>>>(Hacc, H2c);
    cin_layer<7, 13, 208, 3><<<dim3(CIN_B / 2, 2), 448, 0, stream>>>(H2c, Xh, Wtk3, nullptr, outp3);

    cin_outc<<<(CIN_B * 400) / 256, 256, 0, stream>>>(outp2, outp3, out);
}

// Round 14
// 281.372 us; speedup vs baseline: 1.2123x; 1.1067x over previous
//
#include <hip/hip_runtime.h>

#define CIN_B 512
#define CIN_F0 40
#define CIN_D 32
#define CIN_S 200

typedef _Float16 f16x8 __attribute__((ext_vector_type(8)));
typedef float floatx16 __attribute__((ext_vector_type(16)));

__device__ __forceinline__ unsigned short f2h(float f) {
    _Float16 h = (_Float16)f;           // RNE
    return *(unsigned short*)&h;
}
__device__ __forceinline__ float h2f(unsigned short u) {
    return (float)(*(_Float16*)&u);
}

// Wtk[kc][nn 0..255][kw 0..15] = f16(W[(i*FI + kk*16+kw)*200 + nn]); kc=i*KCPI+kk.
template <int FI, int KCPI>
__global__ __launch_bounds__(256) void prep_w(const float* __restrict__ W,
                                              unsigned short* __restrict__ Wtk) {
    const int kc = blockIdx.x;
    const int nn = threadIdx.x;
    const int i = kc / KCPI;
    const int kk = kc - i * KCPI;
    unsigned short v[16];
#pragma unroll
    for (int kw = 0; kw < 16; ++kw) {
        int j = kk * 16 + kw;
        float f = 0.f;
        if (j < FI && nn < CIN_S) f = W[(size_t)(i * FI + j) * CIN_S + nn];
        v[kw] = f2h(f);
    }
    uint4* dst = (uint4*)(Wtk + ((size_t)kc * 256 + nn) * 16);
    dst[0] = ((const uint4*)v)[0];
    dst[1] = ((const uint4*)v)[1];
}

// fused for the two big weight matrices; kc = i*13+kk, kk==6 stored 0.5x (read
// by BOTH j-halves: 0.5x + 0.5x == x; 0.5 scaling exact in fp16).
__global__ __launch_bounds__(256) void prep_w2(const float* __restrict__ Wa,
                                               unsigned short* __restrict__ Wta,
                                               const float* __restrict__ Wb,
                                               unsigned short* __restrict__ Wtb) {
    const int half = blockIdx.x >= 520;
    const int kc = half ? blockIdx.x - 520 : blockIdx.x;
    const float* W = half ? Wb : Wa;
    unsigned short* Wtk = half ? Wtb : Wta;
    const int nn = threadIdx.x;
    const int i = kc / 13;
    const int kk = kc - i * 13;
    const float sc = (kk == 6) ? 0.5f : 1.0f;
    unsigned short v[16];
#pragma unroll
    for (int kw = 0; kw < 16; ++kw) {
        int j = kk * 16 + kw;
        float f = 0.f;
        if (j < CIN_S && nn < CIN_S) f = sc * W[(size_t)(i * CIN_S + j) * CIN_S + nn];
        v[kw] = f2h(f);
    }
    uint4* dst = (uint4*)(Wtk + ((size_t)kc * 256 + nn) * 16);
    dst[0] = ((const uint4*)v)[0];
    dst[1] = ((const uint4*)v)[1];
}

// X0hd[b][d][i(pad 48)] = f16(x0[b][i][d]);  Xh[b][i][d] = f16(x0[b][i][d])
__global__ __launch_bounds__(256) void prep_x(const float* __restrict__ X,
                                              unsigned short* __restrict__ X0hd,
                                              unsigned short* __restrict__ Xh) {
    int e = blockIdx.x * 256 + threadIdx.x;   // 512*40*32
    int d = e & 31;
    int rest = e >> 5;
    int i = rest % CIN_F0;
    int b = rest / CIN_F0;
    unsigned short v = f2h(X[e]);
    Xh[e] = v;
    X0hd[((size_t)b * CIN_D + d) * 48 + i] = v;
    if (e < CIN_B * CIN_D * 8) {     // zero pads i=40..47
        int q = e & 7, dd = (e >> 3) & 31, bb = e >> 8;
        X0hd[((size_t)bb * CIN_D + dd) * 48 + 40 + q] = 0;
    }
}

// One layer (j-half per blockIdx.y for MODE 2/3). Block = 2 b x 7 waves (448).
// R10 skeleton (best measured) + i2-blocking: loop i2 outer (step 2), kk inner;
// per (i2,kk) the 2 B-frags are read from LDS ONCE and feed 4 MFMAs (2i x 2b)
// -> B ds_reads halved to 280/wave; the 2 independent A-loads per kk give ILP.
// A: plain global loads (L2-resident Wtk); x: packed pairs staged in LDS.
// mfma_f32_32x32x16_f16: A[m=lane&31][k=(lane>>5)*8+e]; B[k][col=lane&31];
// C/D col=lane&31, row=(reg&3)+8*(reg>>2)+4*(lane>>5).
template <int NKC, int KCPI_TOT, int JROW, int MODE>
__global__ __launch_bounds__(448, 4)
void cin_layer(const unsigned short* __restrict__ Hsrc,
               const unsigned short* __restrict__ Xh,
               const unsigned short* __restrict__ Wtk,
               unsigned short* __restrict__ Hout,
               float* __restrict__ outp) {
    __shared__ __align__(16) unsigned short Bp[2 * NKC * 512];   // 6 / 14 KB
    __shared__ unsigned int Xl[CIN_F0 * CIN_D];                  // 5 KB

    const int tid = threadIdx.x;
    const int b0 = blockIdx.x * 2;
    const int jh = (MODE == 1) ? 0 : blockIdx.y;
    const int kks = jh * 6;

    // stage packed x-pairs: Xl[i*32+d] = x[b0][i][d] | x[b0+1][i][d]<<16
    for (int e = tid; e < CIN_F0 * CIN_D; e += 448) {
        unsigned int lo = Xh[(size_t)b0 * (CIN_F0 * CIN_D) + e];
        unsigned int hi = Xh[(size_t)(b0 + 1) * (CIN_F0 * CIN_D) + e];
        Xl[e] = lo | (hi << 16);
    }
    // stage B-frags into LDS (fragment order, i-invariant) — R10/R13 layout
    {
        const int j0 = (MODE == 1) ? 0 : jh * 96;
        uint4* Bpu = (uint4*)Bp;
        for (int g = tid; g < 2 * 64 * NKC; g += 448) {
            int bb = g / (64 * NKC), r = g - bb * (64 * NKC);
            int d = r / (2 * NKC), c = r - d * (2 * NKC);
            uint4 v = ((const uint4*)Hsrc)[(((size_t)(b0 + bb) * CIN_D + d) * JROW + j0) / 8 + c];
            Bpu[(bb * NKC + (c >> 1)) * 64 + (c & 1) * 32 + d] = v;
        }
    }
    __syncthreads();

    const int wave = tid >> 6, lane = tid & 63;
    const int l32 = lane & 31, hl = lane >> 5;
    const int tile = wave;

    const unsigned short* Abase =
        Wtk + ((size_t)(tile * 32 + l32) * 16 + hl * 8) + (size_t)kks * 4096;

    floatx16 acc0, acc1;
#pragma unroll
    for (int r = 0; r < 16; ++r) { acc0[r] = 0.f; acc1[r] = 0.f; }

#pragma unroll 1
    for (int i2 = 0; i2 < CIN_F0; i2 += 2) {
        const unsigned int xpa = Xl[i2 * CIN_D + l32];
        const unsigned int xpb = Xl[(i2 + 1) * CIN_D + l32];
        union { f16x8 v; unsigned int w[4]; } xs0a, xs1a, xs0b, xs1b;
        {
            const unsigned int lo2a = (xpa & 0xffffu) | (xpa << 16);
            const unsigned int hi2a = (xpa >> 16) | (xpa & 0xffff0000u);
            const unsigned int lo2b = (xpb & 0xffffu) | (xpb << 16);
            const unsigned int hi2b = (xpb >> 16) | (xpb & 0xffff0000u);
#pragma unroll
            for (int q = 0; q < 4; ++q) {
                xs0a.w[q] = lo2a; xs1a.w[q] = hi2a;
                xs0b.w[q] = lo2b; xs1b.w[q] = hi2b;
            }
        }
        const unsigned short* Aia = Abase + (size_t)i2 * (KCPI_TOT * 4096);
        const unsigned short* Aib = Aia + (size_t)(KCPI_TOT * 4096);
#pragma unroll
        for (int kk = 0; kk < NKC; ++kk) {
            const f16x8 Afa = *(const f16x8*)(Aia + kk * 4096);
            const f16x8 Afb = *(const f16x8*)(Aib + kk * 4096);
            const f16x8 B0 = *(const f16x8*)&Bp[(0 * NKC + kk) * 512 + lane * 8];
            const f16x8 B1 = *(const f16x8*)&Bp[(1 * NKC + kk) * 512 + lane * 8];
            acc0 = __builtin_amdgcn_mfma_f32_32x32x16_f16(Afa, B0 * xs0a.v, acc0, 0, 0, 0);
            acc1 = __builtin_amdgcn_mfma_f32_32x32x16_f16(Afa, B1 * xs1a.v, acc1, 0, 0, 0);
            acc0 = __builtin_amdgcn_mfma_f32_32x32x16_f16(Afb, B0 * xs0b.v, acc0, 0, 0, 0);
            acc1 = __builtin_amdgcn_mfma_f32_32x32x16_f16(Afb, B1 * xs1b.v, acc1, 0, 0, 0);
        }
    }

    // ---- epilogue ----
#pragma unroll
    for (int bb = 0; bb < 2; ++bb) {
        const floatx16& a = bb ? acc1 : acc0;

        if constexpr (MODE == 1) {   // H1[b][d][n] f16, n-tile of 32
            unsigned short* dst =
                Hout + ((size_t)(b0 + bb) * CIN_D + l32) * 224 + tile * 32;
#pragma unroll
            for (int qd = 0; qd < 4; ++qd) {
                ushort4 pk;
                pk.x = f2h(a[4 * qd + 0]);
                pk.y = f2h(a[4 * qd + 1]);
                pk.z = f2h(a[4 * qd + 2]);
                pk.w = f2h(a[4 * qd + 3]);
                *(ushort4*)&dst[8 * qd + 4 * hl] = pk;
            }
        }
        if constexpr (MODE == 2) {   // Hacc[jh][b][n][d] f16 partials
            unsigned short* hb2 =
                Hout + (((size_t)jh * CIN_B + b0 + bb) * 208) * CIN_D + l32;
#pragma unroll
            for (int r = 0; r < 16; ++r) {
                int n = tile * 32 + (r & 3) + 8 * (r >> 2) + 4 * hl;
                if (n < 208) hb2[(size_t)n * CIN_D] = f2h(a[r]);
            }
        }

        // d-sum over col = l32 (fp32)
#pragma unroll
        for (int r = 0; r < 16; ++r) {
            float v = a[r];
            v += __shfl_xor(v, 1);
            v += __shfl_xor(v, 2);
            v += __shfl_xor(v, 4);
            v += __shfl_xor(v, 8);
            v += __shfl_xor(v, 16);
            if (l32 == 0) {
                int n = tile * 32 + (r & 3) + 8 * (r >> 2) + 4 * hl;
                if (n < CIN_S) {
                    if constexpr (MODE == 1)
                        outp[(size_t)(b0 + bb) * (3 * CIN_S) + n] = v;   // direct
                    else
                        outp[((size_t)jh * CIN_B + b0 + bb) * CIN_S + n] = v;
                }
            }
        }
    }
}

// combine jh-partials of layer2's H: H2c[b][d][n<208] = p0[b][n][d]+p1[b][n][d]
__global__ __launch_bounds__(256) void cin_comb(const unsigned short* __restrict__ Hacc,
                                                unsigned short* __restrict__ H2c) {
    __shared__ unsigned short T[208][33];
    const int b = blockIdx.x;
    const unsigned short* p0 = Hacc + (size_t)b * 208 * CIN_D;
    const unsigned short* p1 = p0 + (size_t)CIN_B * 208 * CIN_D;
    for (int e = threadIdx.x; e < 208 * CIN_D; e += 256) {
        T[e >> 5][e & 31] = f2h(h2f(p0[e]) + h2f(p1[e]));
    }
    __syncthreads();
    const int d = threadIdx.x >> 3, c = threadIdx.x & 7;   // 32 d x 8 chunks of 26
    unsigned short* dst = H2c + ((size_t)b * CIN_D + d) * 208 + c * 26;
#pragma unroll
    for (int q = 0; q < 26; ++q) dst[q] = T[c * 26 + q][d];
}

// out[b, 200+t] from jh-partial sums (t in [0,400))
__global__ __launch_bounds__(256) void cin_outc(const float* __restrict__ p2,
                                                const float* __restrict__ p3,
                                                float* __restrict__ out) {
    int e = blockIdx.x * 256 + threadIdx.x;   // 512*400 exact
    int b = e / 400, t = e - b * 400;
    int half = t / 200, n = t - half * 200;
    const float* p = half ? p3 : p2;
    out[(size_t)b * 600 + 200 + half * 200 + n] =
        p[(size_t)b * CIN_S + n] + p[(size_t)(CIN_B + b) * CIN_S + n];
}

extern "C" void kernel_launch(void* const* d_in, const int* in_sizes, int n_in,
                              void* d_out, int out_size, void* d_ws, size_t ws_size,
                              hipStream_t stream) {
    const float* X  = (const float*)d_in[0];
    const float* W0 = (const float*)d_in[1];
    const float* W1 = (const float*)d_in[2];
    const float* W2 = (const float*)d_in[3];
    float* out = (float*)d_out;

    unsigned short* Wtk1 = (unsigned short*)d_ws;             // 120*4096
    unsigned short* Wtk2 = Wtk1 + (size_t)120 * 4096;         // 520*4096 each
    unsigned short* Wtk3 = Wtk2 + (size_t)520 * 4096;
    unsigned short* X0hd = Wtk3 + (size_t)520 * 4096;         // 512*32*48
    unsigned short* Xh   = X0hd + (size_t)CIN_B * CIN_D * 48; // 512*40*32
    unsigned short* H1   = Xh + (size_t)CIN_B * CIN_F0 * CIN_D; // 512*32*224
    unsigned short* Hacc = H1 + (size_t)CIN_B * CIN_D * 224;  // 2*512*208*32 f16
    unsigned short* H2c  = Hacc + (size_t)2 * CIN_B * 208 * CIN_D; // 512*32*208
    float* outp2 = (float*)(H2c + (size_t)CIN_B * CIN_D * 208);    // 2*512*200
    float* outp3 = outp2 + (size_t)2 * CIN_B * CIN_S;
    // total ws ~47 MB

    prep_w<CIN_F0, 3><<<120, 256, 0, stream>>>(W0, Wtk1);
    prep_w2<<<1040, 256, 0, stream>>>(W1, Wtk2, W2, Wtk3);
    prep_x<<<(CIN_B * CIN_F0 * CIN_D) / 256, 256, 0, stream>>>(X, X0hd, Xh);

    cin_layer<3, 3, 48, 1><<<dim3(CIN_B / 2, 1), 448, 0, stream>>>(X0hd, Xh, Wtk1, H1, out);
    cin_layer<7, 13, 224, 2><<<dim3(CIN_B / 2, 2), 448, 0, stream>>>(H1, Xh, Wtk2, Hacc, outp2);
    cin_comb<<<CIN_B, 256, 0, stream>>>(Hacc, H2c);
    cin_layer<7, 13, 208, 3><<<dim3(CIN_B / 2, 2), 448, 0, stream>>>(H2c, Xh, Wtk3, nullptr, outp3);

    cin_outc<<<(CIN_B * 400) / 256, 256, 0, stream>>>(outp2, outp3, out);
}

// Round 16
// 279.900 us; speedup vs baseline: 1.2186x; 1.0053x over previous
//
#include <hip/hip_runtime.h>

#define CIN_B 512
#define CIN_F0 40
#define CIN_D 32
#define CIN_S 200

typedef _Float16 f16x8 __attribute__((ext_vector_type(8)));
typedef _Float16 f16x2 __attribute__((ext_vector_type(2)));
typedef float floatx16 __attribute__((ext_vector_type(16)));

__device__ __forceinline__ unsigned short f2h(float f) {
    _Float16 h = (_Float16)f;           // RNE
    return *(unsigned short*)&h;
}
__device__ __forceinline__ float h2f(unsigned short u) {
    return (float)(*(_Float16*)&u);
}
// v * broadcast(s2): 4 v_pk_mul_f16 sharing one scale register
__device__ __forceinline__ f16x8 mulbc(f16x8 v, unsigned int s2) {
    union { unsigned int u; f16x2 p; } sc; sc.u = s2;
    union { f16x8 h; f16x2 p[4]; } a, r;
    a.h = v;
#pragma unroll
    for (int q = 0; q < 4; ++q) r.p[q] = a.p[q] * sc.p;
    return r.h;
}

// Wtk[kc][nn 0..255][kw 0..15] = f16(W[(i*FI + kk*16+kw)*200 + nn]); kc=i*KCPI+kk.
template <int FI, int KCPI>
__global__ __launch_bounds__(256) void prep_w(const float* __restrict__ W,
                                              unsigned short* __restrict__ Wtk) {
    const int kc = blockIdx.x;
    const int nn = threadIdx.x;
    const int i = kc / KCPI;
    const int kk = kc - i * KCPI;
    unsigned short v[16];
#pragma unroll
    for (int kw = 0; kw < 16; ++kw) {
        int j = kk * 16 + kw;
        float f = 0.f;
        if (j < FI && nn < CIN_S) f = W[(size_t)(i * FI + j) * CIN_S + nn];
        v[kw] = f2h(f);
    }
    uint4* dst = (uint4*)(Wtk + ((size_t)kc * 256 + nn) * 16);
    dst[0] = ((const uint4*)v)[0];
    dst[1] = ((const uint4*)v)[1];
}

// fused for the two big weight matrices; kc = i*13+kk, kk==6 stored 0.5x (read
// by BOTH j-halves: 0.5x + 0.5x == x; 0.5 scaling exact in fp16).
__global__ __launch_bounds__(256) void prep_w2(const float* __restrict__ Wa,
                                               unsigned short* __restrict__ Wta,
                                               const float* __restrict__ Wb,
                                               unsigned short* __restrict__ Wtb) {
    const int half = blockIdx.x >= 520;
    const int kc = half ? blockIdx.x - 520 : blockIdx.x;
    const float* W = half ? Wb : Wa;
    unsigned short* Wtk = half ? Wtb : Wta;
    const int nn = threadIdx.x;
    const int i = kc / 13;
    const int kk = kc - i * 13;
    const float sc = (kk == 6) ? 0.5f : 1.0f;
    unsigned short v[16];
#pragma unroll
    for (int kw = 0; kw < 16; ++kw) {
        int j = kk * 16 + kw;
        float f = 0.f;
        if (j < CIN_S && nn < CIN_S) f = sc * W[(size_t)(i * CIN_S + j) * CIN_S + nn];
        v[kw] = f2h(f);
    }
    uint4* dst = (uint4*)(Wtk + ((size_t)kc * 256 + nn) * 16);
    dst[0] = ((const uint4*)v)[0];
    dst[1] = ((const uint4*)v)[1];
}

// X0hd[b][d][i(pad 48)] = f16(x0[b][i][d]);  Xh[b][i][d] = f16(x0[b][i][d])
__global__ __launch_bounds__(256) void prep_x(const float* __restrict__ X,
                                              unsigned short* __restrict__ X0hd,
                                              unsigned short* __restrict__ Xh) {
    int e = blockIdx.x * 256 + threadIdx.x;   // 512*40*32
    int d = e & 31;
    int rest = e >> 5;
    int i = rest % CIN_F0;
    int b = rest / CIN_F0;
    unsigned short v = f2h(X[e]);
    Xh[e] = v;
    X0hd[((size_t)b * CIN_D + d) * 48 + i] = v;
    if (e < CIN_B * CIN_D * 8) {     // zero pads i=40..47
        int q = e & 7, dd = (e >> 3) & 31, bb = e >> 8;
        X0hd[((size_t)bb * CIN_D + dd) * 48 + 40 + q] = 0;
    }
}

// One layer (j-half per blockIdx.y for MODE 2/3). Block = 2 b x 7 waves (448).
// R14 skeleton + FORCED software pipeline: flattened steps s=(i2,kk), body
// unrolled 2*NKC (all indices literal), loop-carried rotation regs:
//   Ar[2][2]: A-fragments prefetched 2 steps ahead (issued AFTER the MFMAs)
//   Br[2][2]: B-fragments (LDS) prefetched 1 step ahead
// Loop-carried values cannot be rematerialized -> allocator must fund them
// (R5-R14: every optional hoist was refused; this one is mandatory).
// xs scales update only at kk==0. acc is the MFMA C operand (32 AGPRs).
// mfma_f32_32x32x16_f16: A[m=lane&31][k=(lane>>5)*8+e]; B[k][col=lane&31];
// C/D col=lane&31, row=(reg&3)+8*(reg>>2)+4*(lane>>5).
template <int NKC, int KCPI_TOT, int JROW, int MODE>
__global__ __launch_bounds__(448, 4)
void cin_layer(const unsigned short* __restrict__ Hsrc,
               const unsigned short* __restrict__ Xh,
               const unsigned short* __restrict__ Wtk,
               unsigned short* __restrict__ Hout,
               float* __restrict__ outp) {
    __shared__ __align__(16) unsigned short Bp[2 * NKC * 512];   // 6 / 14 KB
    __shared__ unsigned int Xl[CIN_F0 * CIN_D];                  // 5 KB

    const int tid = threadIdx.x;
    const int b0 = blockIdx.x * 2;
    const int jh = (MODE == 1) ? 0 : blockIdx.y;
    const int kks = jh * 6;

    // stage packed x-pairs: Xl[i*32+d] = x[b0][i][d] | x[b0+1][i][d]<<16
    for (int e = tid; e < CIN_F0 * CIN_D; e += 448) {
        unsigned int lo = Xh[(size_t)b0 * (CIN_F0 * CIN_D) + e];
        unsigned int hi = Xh[(size_t)(b0 + 1) * (CIN_F0 * CIN_D) + e];
        Xl[e] = lo | (hi << 16);
    }
    // stage B-frags into LDS (fragment order, i-invariant) — R10/R13 layout
    {
        const int j0 = (MODE == 1) ? 0 : jh * 96;
        uint4* Bpu = (uint4*)Bp;
        for (int g = tid; g < 2 * 64 * NKC; g += 448) {
            int bb = g / (64 * NKC), r = g - bb * (64 * NKC);
            int d = r / (2 * NKC), c = r - d * (2 * NKC);
            uint4 v = ((const uint4*)Hsrc)[(((size_t)(b0 + bb) * CIN_D + d) * JROW + j0) / 8 + c];
            Bpu[(bb * NKC + (c >> 1)) * 64 + (c & 1) * 32 + d] = v;
        }
    }
    __syncthreads();

    const int wave = tid >> 6, lane = tid & 63;
    const int l32 = lane & 31, hl = lane >> 5;
    const int tile = wave;

    const int aB = (tile * 32 + l32) * 16 + hl * 8;   // per-lane element offset
    constexpr int NS = 20 * NKC;

    f16x8 Ar[2][2];   // [slot][0: i=iA, 1: i=iA+1]
    f16x8 Br[2][2];   // [slot][b-index]

    auto ldA = [&](int s, int slot) {
        int ss = (s < NS) ? s : (NS - 1);
        int iA = 2 * (ss / NKC), kk = ss % NKC;
        int e = (iA * KCPI_TOT + kks + kk) * 4096 + aB;
        Ar[slot][0] = *(const f16x8*)(Wtk + e);
        Ar[slot][1] = *(const f16x8*)(Wtk + e + KCPI_TOT * 4096);
    };
    auto ldB = [&](int s, int slot) {
        int ss = (s < NS) ? s : (NS - 1);
        int kk = ss % NKC;
        Br[slot][0] = *(const f16x8*)&Bp[(0 * NKC + kk) * 512 + lane * 8];
        Br[slot][1] = *(const f16x8*)&Bp[(1 * NKC + kk) * 512 + lane * 8];
    };

    ldA(0, 0);
    ldA(1, 1);
    ldB(0, 0);

    floatx16 acc0, acc1;
#pragma unroll
    for (int r = 0; r < 16; ++r) { acc0[r] = 0.f; acc1[r] = 0.f; }
    unsigned int xs0a = 0, xs1a = 0, xs0b = 0, xs1b = 0;

#pragma unroll 1
    for (int s0 = 0; s0 < NS; s0 += 2 * NKC) {
#pragma unroll
        for (int t = 0; t < 2 * NKC; ++t) {
            const int s = s0 + t;
            const int kk = t % NKC;                   // literal
            if (kk == 0) {                            // xs update (2x per body)
                const int iA = (s0 / NKC + (t ? 1 : 0)) * 2;
                unsigned int xpa = Xl[iA * CIN_D + l32];
                unsigned int xpb = Xl[(iA + 1) * CIN_D + l32];
                xs0a = (xpa & 0xffffu) | (xpa << 16);
                xs1a = (xpa >> 16) | (xpa & 0xffff0000u);
                xs0b = (xpb & 0xffffu) | (xpb << 16);
                xs1b = (xpb >> 16) | (xpb & 0xffff0000u);
            }
            ldB(s + 1, (t + 1) & 1);                  // B prefetch, 1 ahead
            const int sl = t & 1;
            acc0 = __builtin_amdgcn_mfma_f32_32x32x16_f16(
                Ar[sl][0], mulbc(Br[sl][0], xs0a), acc0, 0, 0, 0);
            acc1 = __builtin_amdgcn_mfma_f32_32x32x16_f16(
                Ar[sl][0], mulbc(Br[sl][1], xs1a), acc1, 0, 0, 0);
            acc0 = __builtin_amdgcn_mfma_f32_32x32x16_f16(
                Ar[sl][1], mulbc(Br[sl][0], xs0b), acc0, 0, 0, 0);
            acc1 = __builtin_amdgcn_mfma_f32_32x32x16_f16(
                Ar[sl][1], mulbc(Br[sl][1], xs1b), acc1, 0, 0, 0);
            ldA(s + 2, sl);                           // A prefetch, 2 ahead
        }
    }

    // ---- epilogue ----
#pragma unroll
    for (int bb = 0; bb < 2; ++bb) {
        const floatx16& a = bb ? acc1 : acc0;

        if constexpr (MODE == 1) {   // H1[b][d][n] f16, n-tile of 32
            unsigned short* dst =
                Hout + ((size_t)(b0 + bb) * CIN_D + l32) * 224 + tile * 32;
#pragma unroll
            for (int qd = 0; qd < 4; ++qd) {
                ushort4 pk;
                pk.x = f2h(a[4 * qd + 0]);
                pk.y = f2h(a[4 * qd + 1]);
                pk.z = f2h(a[4 * qd + 2]);
                pk.w = f2h(a[4 * qd + 3]);
                *(ushort4*)&dst[8 * qd + 4 * hl] = pk;
            }
        }
        if constexpr (MODE == 2) {   // Hacc[jh][b][n][d] f16 partials
            unsigned short* hb2 =
                Hout + (((size_t)jh * CIN_B + b0 + bb) * 208) * CIN_D + l32;
#pragma unroll
            for (int r = 0; r < 16; ++r) {
                int n = tile * 32 + (r & 3) + 8 * (r >> 2) + 4 * hl;
                if (n < 208) hb2[(size_t)n * CIN_D] = f2h(a[r]);
            }
        }

        // d-sum over col = l32 (fp32)
#pragma unroll
        for (int r = 0; r < 16; ++r) {
            float v = a[r];
            v += __shfl_xor(v, 1);
            v += __shfl_xor(v, 2);
            v += __shfl_xor(v, 4);
            v += __shfl_xor(v, 8);
            v += __shfl_xor(v, 16);
            if (l32 == 0) {
                int n = tile * 32 + (r & 3) + 8 * (r >> 2) + 4 * hl;
                if (n < CIN_S) {
                    if constexpr (MODE == 1)
                        outp[(size_t)(b0 + bb) * (3 * CIN_S) + n] = v;   // direct
                    else
                        outp[((size_t)jh * CIN_B + b0 + bb) * CIN_S + n] = v;
                }
            }
        }
    }
}

// combine jh-partials of layer2's H: H2c[b][d][n<208] = p0[b][n][d]+p1[b][n][d]
__global__ __launch_bounds__(256) void cin_comb(const unsigned short* __restrict__ Hacc,
                                                unsigned short* __restrict__ H2c) {
    __shared__ unsigned short T[208][33];
    const int b = blockIdx.x;
    const unsigned short* p0 = Hacc + (size_t)b * 208 * CIN_D;
    const unsigned short* p1 = p0 + (size_t)CIN_B * 208 * CIN_D;
    for (int e = threadIdx.x; e < 208 * CIN_D; e += 256) {
        T[e >> 5][e & 31] = f2h(h2f(p0[e]) + h2f(p1[e]));
    }
    __syncthreads();
    const int d = threadIdx.x >> 3, c = threadIdx.x & 7;   // 32 d x 8 chunks of 26
    unsigned short* dst = H2c + ((size_t)b * CIN_D + d) * 208 + c * 26;
#pragma unroll
    for (int q = 0; q < 26; ++q) dst[q] = T[c * 26 + q][d];
}

// out[b, 200+t] from jh-partial sums (t in [0,400))
__global__ __launch_bounds__(256) void cin_outc(const float* __restrict__ p2,
                                                const float* __restrict__ p3,
                                                float* __restrict__ out) {
    int e = blockIdx.x * 256 + threadIdx.x;   // 512*400 exact
    int b = e / 400, t = e - b * 400;
    int half = t / 200, n = t - half * 200;
    const float* p = half ? p3 : p2;
    out[(size_t)b * 600 + 200 + half * 200 + n] =
        p[(size_t)b * CIN_S + n] + p[(size_t)(CIN_B + b) * CIN_S + n];
}

extern "C" void kernel_launch(void* const* d_in, const int* in_sizes, int n_in,
                              void* d_out, int out_size, void* d_ws, size_t ws_size,
                              hipStream_t stream) {
    const float* X  = (const float*)d_in[0];
    const float* W0 = (const float*)d_in[1];
    const float* W1 = (const float*)d_in[2];
    const float* W2 = (const float*)d_in[3];
    float* out = (float*)d_out;

    unsigned short* Wtk1 = (unsigned short*)d_ws;             // 120*4096
    unsigned short* Wtk2 = Wtk1 + (size_t)120 * 4096;         // 520*4096 each
    unsigned short* Wtk3 = Wtk2 + (size_t)520 * 4096;
    unsigned short* X0hd = Wtk3 + (size_t)520 * 4096;         // 512*32*48
    unsigned short* Xh   = X0hd + (size_t)CIN_B * CIN_D * 48; // 512*40*32
    unsigned short* H1   = Xh + (size_t)CIN_B * CIN_F0 * CIN_D; // 512*32*224
    unsigned short* Hacc = H1 + (size_t)CIN_B * CIN_D * 224;  // 2*512*208*32 f16
    unsigned short* H2c  = Hacc + (size_t)2 * CIN_B * 208 * CIN_D; // 512*32*208
    float* outp2 = (float*)(H2c + (size_t)CIN_B * CIN_D * 208);    // 2*512*200
    float* outp3 = outp2 + (size_t)2 * CIN_B * CIN_S;
    // total ws ~47 MB

    prep_w<CIN_F0, 3><<<120, 256, 0, stream>>>(W0, Wtk1);
    prep_w2<<<1040, 256, 0, stream>>>(W1, Wtk2, W2, Wtk3);
    prep_x<<<(CIN_B * CIN_F0 * CIN_D) / 256, 256, 0, stream>>>(X, X0hd, Xh);

    cin_layer<3, 3, 48, 1><<<dim3(CIN_B / 2, 1), 448, 0, stream>>>(X0hd, Xh, Wtk1, H1, out);
    cin_layer<7, 13, 224, 2><<<dim3(CIN_B / 2, 2), 448, 0, stream>>>(H1, Xh, Wtk2, Hacc, outp2);
    cin_comb<<<CIN_B, 256, 0, stream>>>(Hacc, H2c);
    cin_layer<7, 13, 208, 3><<<dim3(CIN_B / 2, 2), 448, 0, stream>>>(H2c, Xh, Wtk3, nullptr, outp3);

    cin_outc<<<(CIN_B * 400) / 256, 256, 0, stream>>>(outp2, outp3, out);
}